// Round 1
// 577.032 us; speedup vs baseline: 1.0139x; 1.0139x over previous
//
#include <hip/hip_runtime.h>
#include <hip/hip_bf16.h>

// SparseMoE: N=2048, D_IN=1024, D_HID=4096, D_OUT=1024, E=8, K=2.
// R3: (1) XOR-swizzled LDS (chunk ^= (row>>1)&3, both-sides involution per
// rule 21) to kill the 8-way bank conflict on fragment ds_read_b128;
// (2) 2-phase double-buffered K-loop (T3-minimum: issue next tile's
// global_load_lds before current tile's ds_read+MFMA);
// (3) GEMM2 split-K=2 with plain fp32 partial stores (no atomics, no Y
// memset), partials summed in combine; (4) single fused weight-convert launch.

#define N_TOK   2048
#define D_IN    1024
#define D_HID   4096
#define D_OUT   1024
#define NEXP    8
#define TOPK    2
#define ROW_CAP 5120   // max padded rows: 4096 + 8*127 = 5112, round up

typedef __bf16 bf16x8 __attribute__((ext_vector_type(8)));
typedef float  f32x4  __attribute__((ext_vector_type(4)));

__device__ inline unsigned short f2bf(float f) {
    union { float f; unsigned u; } v; v.f = f;
    unsigned u = v.u;
    return (unsigned short)((u + 0x7FFFu + ((u >> 16) & 1u)) >> 16);  // RNE
}
__device__ inline unsigned pack2(float lo, float hi) {
    return (unsigned)f2bf(lo) | ((unsigned)f2bf(hi) << 16);
}
__device__ inline void async_copy16(const void* g, void* l) {
    __builtin_amdgcn_global_load_lds(
        (const __attribute__((address_space(1))) void*)g,
        (__attribute__((address_space(3))) void*)l, 16, 0, 0);
}

// ---------------- weight convert: fp32 -> bf16, both tensors, one launch ----
__global__ __launch_bounds__(256) void convert_w2(
    const float4* __restrict__ s1, uint2* __restrict__ d1, int n1,
    const float4* __restrict__ s2, uint2* __restrict__ d2, int n2)
{
    int idx = blockIdx.x * 256 + threadIdx.x;
    int stride = gridDim.x * 256;
    int ntot = n1 + n2;
    for (int i = idx; i < ntot; i += stride) {
        const float4* s = (i < n1) ? (s1 + i) : (s2 + (i - n1));
        uint2*       d  = (i < n1) ? (d1 + i) : (d2 + (i - n1));
        float4 f = *s;
        uint2 p; p.x = pack2(f.x, f.y); p.y = pack2(f.z, f.w);
        *d = p;
    }
}

// ---------------- gate: 1 wave per token ----------------
__global__ __launch_bounds__(256) void gate_kernel(
    const float* __restrict__ x, const float* __restrict__ gw,
    const float* __restrict__ gb, int* __restrict__ topi,
    float* __restrict__ topw, int* __restrict__ counts)
{
    int wave = threadIdx.x >> 6, lane = threadIdx.x & 63;
    int t = blockIdx.x * 4 + wave;
    const float* xt = x + (size_t)t * D_IN;
    float acc[NEXP];
#pragma unroll
    for (int e = 0; e < NEXP; e++) acc[e] = 0.f;
    for (int i = 0; i < D_IN / 64; i++) {
        float xv = xt[lane + 64 * i];
#pragma unroll
        for (int e = 0; e < NEXP; e++)
            acc[e] += xv * gw[e * D_IN + lane + 64 * i];
    }
#pragma unroll
    for (int e = 0; e < NEXP; e++) {
        float v = acc[e];
#pragma unroll
        for (int m = 32; m; m >>= 1) v += __shfl_xor(v, m, 64);
        acc[e] = v + gb[e];
    }
    if (lane == 0) {
        float b1v = -1e30f; int i1 = 0;
#pragma unroll
        for (int e = 0; e < NEXP; e++) if (acc[e] > b1v) { b1v = acc[e]; i1 = e; }
        float b2v = -1e30f; int i2 = 0;
#pragma unroll
        for (int e = 0; e < NEXP; e++) if (e != i1 && acc[e] > b2v) { b2v = acc[e]; i2 = e; }
        float e2 = __expf(b2v - b1v);
        float inv = 1.f / (1.f + e2);
        topi[t * 2] = i1; topi[t * 2 + 1] = i2;
        topw[t * 2] = inv; topw[t * 2 + 1] = e2 * inv;
        atomicAdd(&counts[i1], 1);
        atomicAdd(&counts[i2], 1);
    }
}

// ---------------- scan: 128-padded exclusive prefix ----------------
__global__ void scan_kernel(const int* __restrict__ counts,
                            int* __restrict__ offsets, int* __restrict__ cursor)
{
    if (threadIdx.x == 0 && blockIdx.x == 0) {
        int off = 0;
        for (int e = 0; e < NEXP; e++) {
            offsets[e] = off;
            cursor[e]  = off;
            off += (counts[e] + 127) & ~127;
        }
    }
}

// ---------------- gather: one wave per (token, k) slot ----------------
__global__ __launch_bounds__(64) void gather_kernel(
    const float* __restrict__ x, const int* __restrict__ topi,
    int* __restrict__ cursor, int* __restrict__ slot_of,
    unsigned short* __restrict__ Xe)
{
    int b = blockIdx.x;          // 0..N*TOPK-1
    int t = b >> 1;
    __shared__ int spos;
    if (threadIdx.x == 0) {
        int e = topi[b];
        int pos = atomicAdd(&cursor[e], 1);
        slot_of[b] = pos;
        spos = pos;
    }
    __syncthreads();
    int pos = spos;
    const float* src = x + (size_t)t * D_IN;
    unsigned short* dst = Xe + (size_t)pos * D_IN;
    int l = threadIdx.x;
#pragma unroll
    for (int i = 0; i < 4; i++) {
        float4 f = *(const float4*)(src + l * 4 + i * 256);
        uint2 p; p.x = pack2(f.x, f.y); p.y = pack2(f.z, f.w);
        *(uint2*)(dst + l * 4 + i * 256) = p;
    }
}

// ---------------- grouped GEMM (bf16, 128x128, dbuf + LDS swizzle) ---------
// A: [rows, KDIM] bf16. Wb: [E, NDIM, KDIM] bf16. Tile 128x128, BK=32,
// 4 waves x (4x4) 16x16x32 MFMA, double-buffered LDS (2-phase pipeline).
// LDS swizzle: each 64B row of a tile holds 4x16B chunks; slot (row, c)
// stores global chunk c ^ ((row>>1)&3). Staging pre-permutes the GLOBAL
// source address (LDS dest of global_load_lds stays linear); ds_read applies
// the same XOR. 16-lane fragment groups then spread across 8 bank-quads
// (2-way = free) instead of 2 (8-way conflict).
// OUT_MODE: 0 = fp32 store (+bias), 1 = bf16 store (+bias),
//           3 = fp32 partial store (kc==0 -> Out, kc==1 -> Out2), no bias
template <int KDIM, int NDIM, int SPLITK, bool RELU, int OUT_MODE>
__global__ __launch_bounds__(256) void moe_gemm(
    const unsigned short* __restrict__ A, const unsigned short* __restrict__ Wb,
    const float* __restrict__ bias, void* __restrict__ Out, void* __restrict__ Out2,
    const int* __restrict__ counts, const int* __restrict__ offsets)
{
    constexpr int KCHUNK = KDIM / SPLITK;
    constexpr int NSTEP  = KCHUNK / 32;
    int e  = blockIdx.z / SPLITK;
    int kc = blockIdx.z % SPLITK;
    int cnt = counts[e];
    int tm = blockIdx.y;
    if (tm * 128 >= cnt) return;
    int m0 = offsets[e] + tm * 128;
    int n0 = blockIdx.x * 128;

    __shared__ __align__(16) unsigned short As[2][128 * 32];
    __shared__ __align__(16) unsigned short Bs[2][128 * 32];

    int tid = threadIdx.x;
    int wave = tid >> 6, lane = tid & 63;

    const unsigned short* We = Wb + (size_t)e * NDIM * KDIM;

    f32x4 acc[4][4];
#pragma unroll
    for (int i = 0; i < 4; i++)
#pragma unroll
        for (int j = 0; j < 4; j++) acc[i][j] = (f32x4){0.f, 0.f, 0.f, 0.f};

    int m_off = (wave & 1) * 64;
    int n_off = (wave >> 1) * 64;

    // staging: segment s covers rows 16s..16s+15, LDS bytes [s*1024, +1024)
    // lane -> row = seg*16 + (lane>>2); global 16B chunk pre-swizzled:
    // (lane&3) ^ ((row>>1)&3) = (lane&3) ^ ((lane>>3)&3)
    int srow   = lane >> 2;
    int schunk = (((lane & 3) ^ ((lane >> 3) & 3)) << 4);

    const char* Ab0 = (const char*)(A  + (size_t)(m0 + wave * 16 + srow) * KDIM) + schunk;
    const char* Ab1 = (const char*)(A  + (size_t)(m0 + (wave + 4) * 16 + srow) * KDIM) + schunk;
    const char* Bb0 = (const char*)(We + (size_t)(n0 + wave * 16 + srow) * KDIM) + schunk;
    const char* Bb1 = (const char*)(We + (size_t)(n0 + (wave + 4) * 16 + srow) * KDIM) + schunk;

#define STAGE(buf, kbyte) do {                                          \
        async_copy16(Ab0 + (kbyte), (char*)As[buf] + wave * 1024);      \
        async_copy16(Ab1 + (kbyte), (char*)As[buf] + (wave + 4) * 1024);\
        async_copy16(Bb0 + (kbyte), (char*)Bs[buf] + wave * 1024);      \
        async_copy16(Bb1 + (kbyte), (char*)Bs[buf] + (wave + 4) * 1024);\
    } while (0)

    int kbyte0 = kc * KCHUNK * 2;
    STAGE(0, kbyte0);
    __syncthreads();   // drains vmcnt: buffer 0 ready

    // fragment read: row r, want global chunk (lane>>4) -> read LDS chunk
    // (lane>>4) ^ ((r>>1)&3); bits 1-2 of r equal bits 1-2 of lane.
    int rchunk = (((lane >> 4) ^ ((lane >> 1) & 3)) << 4);

    for (int t = 0; t < NSTEP; ++t) {
        int cur = t & 1;
        if (t + 1 < NSTEP) STAGE(cur ^ 1, kbyte0 + (t + 1) * 64);  // prefetch

        const char* as_c = (const char*)As[cur];
        const char* bs_c = (const char*)Bs[cur];
        bf16x8 af[4], bfr[4];
#pragma unroll
        for (int mi = 0; mi < 4; mi++) {
            int r = m_off + mi * 16 + (lane & 15);
            af[mi] = *(const bf16x8*)(as_c + r * 64 + rchunk);
        }
#pragma unroll
        for (int ni = 0; ni < 4; ni++) {
            int r = n_off + ni * 16 + (lane & 15);
            bfr[ni] = *(const bf16x8*)(bs_c + r * 64 + rchunk);
        }
#pragma unroll
        for (int mi = 0; mi < 4; mi++)
#pragma unroll
            for (int ni = 0; ni < 4; ni++)
                acc[mi][ni] = __builtin_amdgcn_mfma_f32_16x16x32_bf16(
                    af[mi], bfr[ni], acc[mi][ni], 0, 0, 0);

        __syncthreads();   // drains vmcnt (prefetch) + all lgkm before reuse
    }
#undef STAGE

    // epilogue: C/D map col=lane&15, row=(lane>>4)*4+r
#pragma unroll
    for (int ni = 0; ni < 4; ni++) {
        int col = n0 + n_off + ni * 16 + (lane & 15);
        float bv = (OUT_MODE == 3) ? 0.f : bias[(size_t)e * NDIM + col];
#pragma unroll
        for (int mi = 0; mi < 4; mi++) {
            int row = m0 + m_off + mi * 16 + ((lane >> 4) * 4);
#pragma unroll
            for (int r2 = 0; r2 < 4; r2++) {
                float v = acc[mi][ni][r2] + bv;
                if (RELU) v = fmaxf(v, 0.f);
                if (OUT_MODE == 1)
                    ((unsigned short*)Out)[(size_t)(row + r2) * NDIM + col] = f2bf(v);
                else if (OUT_MODE == 0)
                    ((float*)Out)[(size_t)(row + r2) * NDIM + col] = v;
                else {  // 3: fp32 partial store, no atomics
                    float* o = (kc == 0) ? (float*)Out : (float*)Out2;
                    o[(size_t)(row + r2) * NDIM + col] = v;
                }
            }
        }
    }
}

// ---------------- combine: out[t] = sum_k w_k * (sum_parts Y[s_k] + b2[e_k])
__global__ __launch_bounds__(256) void combine_kernel(
    const float* __restrict__ Y0, const float* __restrict__ Y1,
    const int* __restrict__ slot_of, const int* __restrict__ topi,
    const float* __restrict__ topw, const float* __restrict__ b2,
    float* __restrict__ out)
{
    int t = blockIdx.x;
    int s0 = slot_of[t * 2], s1 = slot_of[t * 2 + 1];
    int e0 = topi[t * 2],    e1 = topi[t * 2 + 1];
    float w0 = topw[t * 2],  w1 = topw[t * 2 + 1];
    int i = threadIdx.x;
    float4 y0 = *(const float4*)(Y0 + (size_t)s0 * D_OUT + i * 4);
    float4 y1 = *(const float4*)(Y0 + (size_t)s1 * D_OUT + i * 4);
    if (Y1) {
        float4 a0 = *(const float4*)(Y1 + (size_t)s0 * D_OUT + i * 4);
        float4 a1 = *(const float4*)(Y1 + (size_t)s1 * D_OUT + i * 4);
        y0.x += a0.x; y0.y += a0.y; y0.z += a0.z; y0.w += a0.w;
        y1.x += a1.x; y1.y += a1.y; y1.z += a1.z; y1.w += a1.w;
    }
    float4 c0 = *(const float4*)(b2 + (size_t)e0 * D_OUT + i * 4);
    float4 c1 = *(const float4*)(b2 + (size_t)e1 * D_OUT + i * 4);
    float4 o;
    o.x = w0 * (y0.x + c0.x) + w1 * (y1.x + c1.x);
    o.y = w0 * (y0.y + c0.y) + w1 * (y1.y + c1.y);
    o.z = w0 * (y0.z + c0.z) + w1 * (y1.z + c1.z);
    o.w = w0 * (y0.w + c0.w) + w1 * (y1.w + c1.w);
    *(float4*)(out + (size_t)t * D_OUT + i * 4) = o;
}

extern "C" void kernel_launch(void* const* d_in, const int* in_sizes, int n_in,
                              void* d_out, int out_size, void* d_ws, size_t ws_size,
                              hipStream_t stream)
{
    const float* x  = (const float*)d_in[0];
    const float* gw = (const float*)d_in[1];
    const float* gb = (const float*)d_in[2];
    const float* W1 = (const float*)d_in[3];
    const float* b1 = (const float*)d_in[4];
    const float* W2 = (const float*)d_in[5];
    const float* b2 = (const float*)d_in[6];
    float* out = (float*)d_out;

    char* ws = (char*)d_ws;
    int* counts  = (int*)ws;                 // 8 ints
    int* cursor  = counts + 8;               // 8 ints
    int* offsets = counts + 16;              // 8 ints
    int* topi    = counts + 32;              // 4096 ints
    int* slot_of = counts + 32 + 4096;       // 4096 ints
    float* topw  = (float*)(counts + 32 + 8192);  // 4096 floats

    const size_t XE_OFF  = 1ull << 16;
    const size_t H_OFF   = XE_OFF  + (size_t)ROW_CAP * D_IN  * 2;  // +10.5 MB
    const size_t Y_OFF   = H_OFF   + (size_t)ROW_CAP * D_HID * 2;  // +41.9 MB
    const size_t W1B_OFF = Y_OFF   + (size_t)ROW_CAP * D_OUT * 4;  // +21.0 MB
    const size_t W2B_OFF = W1B_OFF + (size_t)NEXP * D_HID * D_IN * 2;  // +67.1 MB
    const size_t Y1_OFF  = W2B_OFF + (size_t)NEXP * D_OUT * D_HID * 2; // +67.1 MB
    unsigned short* Xe  = (unsigned short*)(ws + XE_OFF);
    unsigned short* H   = (unsigned short*)(ws + H_OFF);
    float*          Y   = (float*)(ws + Y_OFF);
    unsigned short* W1b = (unsigned short*)(ws + W1B_OFF);
    unsigned short* W2b = (unsigned short*)(ws + W2B_OFF);

    // second split-K partial lives at the tail; fall back to split-K=1 if the
    // workspace can't hold it (layout below Y1_OFF is unchanged either way)
    bool split2 = ws_size >= Y1_OFF + (size_t)ROW_CAP * D_OUT * 4;
    float* Y1 = split2 ? (float*)(ws + Y1_OFF) : nullptr;

    hipMemsetAsync(d_ws, 0, 128, stream);    // counts + cursor only (no Y memset)

    const int W1_N4 = NEXP * D_HID * D_IN / 4;
    const int W2_N4 = NEXP * D_OUT * D_HID / 4;
    convert_w2<<<4096, 256, 0, stream>>>((const float4*)W1, (uint2*)W1b, W1_N4,
                                         (const float4*)W2, (uint2*)W2b, W2_N4);

    gate_kernel<<<N_TOK / 4, 256, 0, stream>>>(x, gw, gb, topi, topw, counts);
    scan_kernel<<<1, 64, 0, stream>>>(counts, offsets, cursor);
    gather_kernel<<<N_TOK * TOPK, 64, 0, stream>>>(x, topi, cursor, slot_of, Xe);

    // GEMM1: H = relu(Xe @ W1^T + b1), bf16 out
    moe_gemm<D_IN, D_HID, 1, true, 1><<<dim3(D_HID / 128, 16, NEXP), 256, 0, stream>>>(
        Xe, W1b, b1, (void*)H, nullptr, counts, offsets);

    // GEMM2: Y(+Y1) = H @ W2^T partials (b2 folded into combine)
    if (split2) {
        moe_gemm<D_HID, D_OUT, 2, false, 3><<<dim3(D_OUT / 128, 16, NEXP * 2), 256, 0, stream>>>(
            H, W2b, b2, (void*)Y, (void*)Y1, counts, offsets);
    } else {
        moe_gemm<D_HID, D_OUT, 1, false, 3><<<dim3(D_OUT / 128, 16, NEXP), 256, 0, stream>>>(
            H, W2b, b2, (void*)Y, nullptr, counts, offsets);
    }

    combine_kernel<<<N_TOK, 256, 0, stream>>>(Y, Y1, slot_of, topi, topw, b2, out);
}

// Round 2
// 556.936 us; speedup vs baseline: 1.0505x; 1.0361x over previous
//
#include <hip/hip_runtime.h>
#include <hip/hip_bf16.h>

// SparseMoE: N=2048, D_IN=1024, D_HID=4096, D_OUT=1024, E=8, K=2.
// R4: eliminate the weight-convert pass (was 115 us, 384 MB of HBM traffic).
// GEMMs now read fp32 weights directly: B operand is register-staged
// (global fp32 -> regs -> RNE-pack bf16 -> ds_write into swizzled LDS slots,
// T14 issue-early/write-late split), A stays on the async global_load_lds
// path. LDS layout/swizzle and fragment-read path are unchanged from R3
// (2-way bank access), 2-phase double buffer, one barrier per K-step.
// GEMM2 keeps split-K=2 with plain fp32 partial stores summed in combine.

#define N_TOK   2048
#define D_IN    1024
#define D_HID   4096
#define D_OUT   1024
#define NEXP    8
#define TOPK    2
#define ROW_CAP 5120   // max padded rows: 4096 + 8*127 = 5112, round up

typedef __bf16 bf16x8 __attribute__((ext_vector_type(8)));
typedef float  f32x4  __attribute__((ext_vector_type(4)));

__device__ inline unsigned short f2bf(float f) {
    union { float f; unsigned u; } v; v.f = f;
    unsigned u = v.u;
    return (unsigned short)((u + 0x7FFFu + ((u >> 16) & 1u)) >> 16);  // RNE
}
__device__ inline unsigned pack2(float lo, float hi) {
    return (unsigned)f2bf(lo) | ((unsigned)f2bf(hi) << 16);
}
__device__ inline void async_copy16(const void* g, void* l) {
    __builtin_amdgcn_global_load_lds(
        (const __attribute__((address_space(1))) void*)g,
        (__attribute__((address_space(3))) void*)l, 16, 0, 0);
}

// ---------------- gate: 1 wave per token ----------------
__global__ __launch_bounds__(256) void gate_kernel(
    const float* __restrict__ x, const float* __restrict__ gw,
    const float* __restrict__ gb, int* __restrict__ topi,
    float* __restrict__ topw, int* __restrict__ counts)
{
    int wave = threadIdx.x >> 6, lane = threadIdx.x & 63;
    int t = blockIdx.x * 4 + wave;
    const float* xt = x + (size_t)t * D_IN;
    float acc[NEXP];
#pragma unroll
    for (int e = 0; e < NEXP; e++) acc[e] = 0.f;
    for (int i = 0; i < D_IN / 64; i++) {
        float xv = xt[lane + 64 * i];
#pragma unroll
        for (int e = 0; e < NEXP; e++)
            acc[e] += xv * gw[e * D_IN + lane + 64 * i];
    }
#pragma unroll
    for (int e = 0; e < NEXP; e++) {
        float v = acc[e];
#pragma unroll
        for (int m = 32; m; m >>= 1) v += __shfl_xor(v, m, 64);
        acc[e] = v + gb[e];
    }
    if (lane == 0) {
        float b1v = -1e30f; int i1 = 0;
#pragma unroll
        for (int e = 0; e < NEXP; e++) if (acc[e] > b1v) { b1v = acc[e]; i1 = e; }
        float b2v = -1e30f; int i2 = 0;
#pragma unroll
        for (int e = 0; e < NEXP; e++) if (e != i1 && acc[e] > b2v) { b2v = acc[e]; i2 = e; }
        float e2 = __expf(b2v - b1v);
        float inv = 1.f / (1.f + e2);
        topi[t * 2] = i1; topi[t * 2 + 1] = i2;
        topw[t * 2] = inv; topw[t * 2 + 1] = e2 * inv;
        atomicAdd(&counts[i1], 1);
        atomicAdd(&counts[i2], 1);
    }
}

// ---------------- scan: 128-padded exclusive prefix ----------------
__global__ void scan_kernel(const int* __restrict__ counts,
                            int* __restrict__ offsets, int* __restrict__ cursor)
{
    if (threadIdx.x == 0 && blockIdx.x == 0) {
        int off = 0;
        for (int e = 0; e < NEXP; e++) {
            offsets[e] = off;
            cursor[e]  = off;
            off += (counts[e] + 127) & ~127;
        }
    }
}

// ---------------- gather: one wave per (token, k) slot ----------------
__global__ __launch_bounds__(64) void gather_kernel(
    const float* __restrict__ x, const int* __restrict__ topi,
    int* __restrict__ cursor, int* __restrict__ slot_of,
    unsigned short* __restrict__ Xe)
{
    int b = blockIdx.x;          // 0..N*TOPK-1
    int t = b >> 1;
    __shared__ int spos;
    if (threadIdx.x == 0) {
        int e = topi[b];
        int pos = atomicAdd(&cursor[e], 1);
        slot_of[b] = pos;
        spos = pos;
    }
    __syncthreads();
    int pos = spos;
    const float* src = x + (size_t)t * D_IN;
    unsigned short* dst = Xe + (size_t)pos * D_IN;
    int l = threadIdx.x;
#pragma unroll
    for (int i = 0; i < 4; i++) {
        float4 f = *(const float4*)(src + l * 4 + i * 256);
        uint2 p; p.x = pack2(f.x, f.y); p.y = pack2(f.z, f.w);
        *(uint2*)(dst + l * 4 + i * 256) = p;
    }
}

// ---------------- grouped GEMM (bf16 MFMA, fp32 weights) -------------------
// A: [rows, KDIM] bf16, async global_load_lds (pre-swizzled global chunk).
// Wf: [E, NDIM, KDIM] fp32, register-staged: thread t loads 16 fp32 of row
// (t>>1), k-half (t&1), packs to bf16, ds_writes into the XOR-swizzled slots.
// LDS tiles stay bf16 [128 rows x 64 B = 4x16B chunks], slot = chunk ^
// ((row>>1)&3) -> fragment ds_read_b128 is 2-way bank access (free).
// 2-phase double buffer, one __syncthreads per K-step:
//   issue loads(t+1) -> ds_read+MFMA(t) -> cvt+ds_write(t+1) -> barrier.
// OUT_MODE: 0 = fp32 store (+bias), 1 = bf16 store (+bias),
//           3 = fp32 partial store (kc==0 -> Out, kc==1 -> Out2), no bias
template <int KDIM, int NDIM, int SPLITK, bool RELU, int OUT_MODE>
__global__ __launch_bounds__(256) void moe_gemm(
    const unsigned short* __restrict__ A, const float* __restrict__ Wf,
    const float* __restrict__ bias, void* __restrict__ Out, void* __restrict__ Out2,
    const int* __restrict__ counts, const int* __restrict__ offsets)
{
    constexpr int KCHUNK = KDIM / SPLITK;
    constexpr int NSTEP  = KCHUNK / 32;
    int e  = blockIdx.z / SPLITK;
    int kc = blockIdx.z % SPLITK;
    int cnt = counts[e];
    int tm = blockIdx.y;
    if (tm * 128 >= cnt) return;
    int m0 = offsets[e] + tm * 128;
    int n0 = blockIdx.x * 128;

    __shared__ __align__(16) unsigned short As[2][128 * 32];
    __shared__ __align__(16) unsigned short Bs[2][128 * 32];

    int tid = threadIdx.x;
    int wave = tid >> 6, lane = tid & 63;

    const float* We = Wf + (size_t)e * NDIM * KDIM;

    f32x4 acc[4][4];
#pragma unroll
    for (int i = 0; i < 4; i++)
#pragma unroll
        for (int j = 0; j < 4; j++) acc[i][j] = (f32x4){0.f, 0.f, 0.f, 0.f};

    int m_off = (wave & 1) * 64;
    int n_off = (wave >> 1) * 64;

    // A staging (async DMA): segment s covers rows 16s..16s+15; lane -> row
    // seg*16 + (lane>>2), global 16B chunk pre-swizzled (lane&3)^((lane>>3)&3)
    int srow   = lane >> 2;
    int schunk = (((lane & 3) ^ ((lane >> 3) & 3)) << 4);
    const char* Ab0 = (const char*)(A + (size_t)(m0 + wave * 16 + srow) * KDIM) + schunk;
    const char* Ab1 = (const char*)(A + (size_t)(m0 + (wave + 4) * 16 + srow) * KDIM) + schunk;

    // B reg staging: thread t covers row t>>1, 16 fp32 at k-offset (t&1)*16
    int brow = tid >> 1;
    const float* Bg = We + (size_t)(n0 + brow) * KDIM + (tid & 1) * 16;
    int bslot0 = ((tid & 1) * 2) ^ ((brow >> 1) & 3);   // second slot = ^1
    char* bw0 = nullptr;  // per-buffer write ptrs computed in WRITE_B

    float4 bq0, bq1, bq2, bq3;

#define STAGE_A(buf, kbyte) do {                                        \
        async_copy16(Ab0 + (kbyte), (char*)As[buf] + wave * 1024);      \
        async_copy16(Ab1 + (kbyte), (char*)As[buf] + (wave + 4) * 1024);\
    } while (0)

#define LOAD_B(kf) do {                                                 \
        bq0 = *(const float4*)(Bg + (kf));                              \
        bq1 = *(const float4*)(Bg + (kf) + 4);                          \
        bq2 = *(const float4*)(Bg + (kf) + 8);                          \
        bq3 = *(const float4*)(Bg + (kf) + 12);                         \
    } while (0)

#define WRITE_B(buf) do {                                               \
        uint4 q0, q1;                                                   \
        q0.x = pack2(bq0.x, bq0.y); q0.y = pack2(bq0.z, bq0.w);         \
        q0.z = pack2(bq1.x, bq1.y); q0.w = pack2(bq1.z, bq1.w);         \
        q1.x = pack2(bq2.x, bq2.y); q1.y = pack2(bq2.z, bq2.w);         \
        q1.z = pack2(bq3.x, bq3.y); q1.w = pack2(bq3.z, bq3.w);         \
        bw0 = (char*)Bs[buf] + brow * 64;                               \
        *(uint4*)(bw0 + bslot0 * 16)       = q0;                        \
        *(uint4*)(bw0 + (bslot0 ^ 1) * 16) = q1;                        \
    } while (0)

    int kf0 = kc * KCHUNK;   // element (fp32/bf16) offset of this K chunk

    // prologue: stage tile 0 into buffer 0
    LOAD_B(kf0);
    STAGE_A(0, kf0 * 2);
    WRITE_B(0);
    __syncthreads();   // drains vmcnt (A DMA) + lgkm (B writes)

    // fragment read: row r, global chunk (lane>>4) -> LDS slot
    // (lane>>4) ^ ((r>>1)&3); bits 1-2 of r equal bits 1-2 of lane.
    int rchunk = (((lane >> 4) ^ ((lane >> 1) & 3)) << 4);

    for (int t = 0; t < NSTEP; ++t) {
        int cur = t & 1;
        bool pf = (t + 1 < NSTEP);
        if (pf) {                                  // issue-early (T14)
            int kf = kf0 + (t + 1) * 32;
            LOAD_B(kf);
            STAGE_A(cur ^ 1, kf * 2);
        }

        const char* as_c = (const char*)As[cur];
        const char* bs_c = (const char*)Bs[cur];
        bf16x8 af[4], bfr[4];
#pragma unroll
        for (int mi = 0; mi < 4; mi++) {
            int r = m_off + mi * 16 + (lane & 15);
            af[mi] = *(const bf16x8*)(as_c + r * 64 + rchunk);
        }
#pragma unroll
        for (int ni = 0; ni < 4; ni++) {
            int r = n_off + ni * 16 + (lane & 15);
            bfr[ni] = *(const bf16x8*)(bs_c + r * 64 + rchunk);
        }
#pragma unroll
        for (int mi = 0; mi < 4; mi++)
#pragma unroll
            for (int ni = 0; ni < 4; ni++)
                acc[mi][ni] = __builtin_amdgcn_mfma_f32_16x16x32_bf16(
                    af[mi], bfr[ni], acc[mi][ni], 0, 0, 0);

        if (pf) WRITE_B(cur ^ 1);                  // write-late (T14)
        __syncthreads();   // next buffer ready; all reads of cur done
    }
#undef STAGE_A
#undef LOAD_B
#undef WRITE_B

    // epilogue: C/D map col=lane&15, row=(lane>>4)*4+r
#pragma unroll
    for (int ni = 0; ni < 4; ni++) {
        int col = n0 + n_off + ni * 16 + (lane & 15);
        float bv = (OUT_MODE == 3) ? 0.f : bias[(size_t)e * NDIM + col];
#pragma unroll
        for (int mi = 0; mi < 4; mi++) {
            int row = m0 + m_off + mi * 16 + ((lane >> 4) * 4);
#pragma unroll
            for (int r2 = 0; r2 < 4; r2++) {
                float v = acc[mi][ni][r2] + bv;
                if (RELU) v = fmaxf(v, 0.f);
                if (OUT_MODE == 1)
                    ((unsigned short*)Out)[(size_t)(row + r2) * NDIM + col] = f2bf(v);
                else if (OUT_MODE == 0)
                    ((float*)Out)[(size_t)(row + r2) * NDIM + col] = v;
                else {  // 3: fp32 partial store, no atomics
                    float* o = (kc == 0) ? (float*)Out : (float*)Out2;
                    o[(size_t)(row + r2) * NDIM + col] = v;
                }
            }
        }
    }
}

// ---------------- combine: out[t] = sum_k w_k * (sum_parts Y[s_k] + b2[e_k])
__global__ __launch_bounds__(256) void combine_kernel(
    const float* __restrict__ Y0, const float* __restrict__ Y1,
    const int* __restrict__ slot_of, const int* __restrict__ topi,
    const float* __restrict__ topw, const float* __restrict__ b2,
    float* __restrict__ out)
{
    int t = blockIdx.x;
    int s0 = slot_of[t * 2], s1 = slot_of[t * 2 + 1];
    int e0 = topi[t * 2],    e1 = topi[t * 2 + 1];
    float w0 = topw[t * 2],  w1 = topw[t * 2 + 1];
    int i = threadIdx.x;
    float4 y0 = *(const float4*)(Y0 + (size_t)s0 * D_OUT + i * 4);
    float4 y1 = *(const float4*)(Y0 + (size_t)s1 * D_OUT + i * 4);
    if (Y1) {
        float4 a0 = *(const float4*)(Y1 + (size_t)s0 * D_OUT + i * 4);
        float4 a1 = *(const float4*)(Y1 + (size_t)s1 * D_OUT + i * 4);
        y0.x += a0.x; y0.y += a0.y; y0.z += a0.z; y0.w += a0.w;
        y1.x += a1.x; y1.y += a1.y; y1.z += a1.z; y1.w += a1.w;
    }
    float4 c0 = *(const float4*)(b2 + (size_t)e0 * D_OUT + i * 4);
    float4 c1 = *(const float4*)(b2 + (size_t)e1 * D_OUT + i * 4);
    float4 o;
    o.x = w0 * (y0.x + c0.x) + w1 * (y1.x + c1.x);
    o.y = w0 * (y0.y + c0.y) + w1 * (y1.y + c1.y);
    o.z = w0 * (y0.z + c0.z) + w1 * (y1.z + c1.z);
    o.w = w0 * (y0.w + c0.w) + w1 * (y1.w + c1.w);
    *(float4*)(out + (size_t)t * D_OUT + i * 4) = o;
}

extern "C" void kernel_launch(void* const* d_in, const int* in_sizes, int n_in,
                              void* d_out, int out_size, void* d_ws, size_t ws_size,
                              hipStream_t stream)
{
    const float* x  = (const float*)d_in[0];
    const float* gw = (const float*)d_in[1];
    const float* gb = (const float*)d_in[2];
    const float* W1 = (const float*)d_in[3];
    const float* b1 = (const float*)d_in[4];
    const float* W2 = (const float*)d_in[5];
    const float* b2 = (const float*)d_in[6];
    float* out = (float*)d_out;

    char* ws = (char*)d_ws;
    int* counts  = (int*)ws;                 // 8 ints
    int* cursor  = counts + 8;               // 8 ints
    int* offsets = counts + 16;              // 8 ints
    int* topi    = counts + 32;              // 4096 ints
    int* slot_of = counts + 32 + 4096;       // 4096 ints
    float* topw  = (float*)(counts + 32 + 8192);  // 4096 floats

    const size_t XE_OFF = 1ull << 16;
    const size_t H_OFF  = XE_OFF + (size_t)ROW_CAP * D_IN  * 2;  // +10.5 MB
    const size_t Y_OFF  = H_OFF  + (size_t)ROW_CAP * D_HID * 2;  // +41.9 MB
    const size_t Y1_OFF = Y_OFF  + (size_t)ROW_CAP * D_OUT * 4;  // +21.0 MB
    unsigned short* Xe = (unsigned short*)(ws + XE_OFF);
    unsigned short* H  = (unsigned short*)(ws + H_OFF);
    float*          Y  = (float*)(ws + Y_OFF);

    // second split-K partial; fall back to split-K=1 if workspace is small
    bool split2 = ws_size >= Y1_OFF + (size_t)ROW_CAP * D_OUT * 4;
    float* Y1 = split2 ? (float*)(ws + Y1_OFF) : nullptr;

    hipMemsetAsync(d_ws, 0, 128, stream);    // counts + cursor only

    gate_kernel<<<N_TOK / 4, 256, 0, stream>>>(x, gw, gb, topi, topw, counts);
    scan_kernel<<<1, 64, 0, stream>>>(counts, offsets, cursor);
    gather_kernel<<<N_TOK * TOPK, 64, 0, stream>>>(x, topi, cursor, slot_of, Xe);

    // GEMM1: H = relu(Xe @ W1^T + b1), bf16 out; W1 consumed as fp32
    moe_gemm<D_IN, D_HID, 1, true, 1><<<dim3(D_HID / 128, 16, NEXP), 256, 0, stream>>>(
        Xe, W1, b1, (void*)H, nullptr, counts, offsets);

    // GEMM2: Y(+Y1) = H @ W2^T partials (b2 folded into combine)
    if (split2) {
        moe_gemm<D_HID, D_OUT, 2, false, 3><<<dim3(D_OUT / 128, 16, NEXP * 2), 256, 0, stream>>>(
            H, W2, b2, (void*)Y, (void*)Y1, counts, offsets);
    } else {
        moe_gemm<D_HID, D_OUT, 1, false, 3><<<dim3(D_OUT / 128, 16, NEXP), 256, 0, stream>>>(
            H, W2, b2, (void*)Y, nullptr, counts, offsets);
    }

    combine_kernel<<<N_TOK, 256, 0, stream>>>(Y, Y1, slot_of, topi, topw, b2, out);
}